// Round 5
// baseline (350.029 us; speedup 1.0000x reference)
//
#include <hip/hip_runtime.h>
#include <hip/hip_cooperative_groups.h>
#include <hip/hip_bf16.h>
#include <math.h>

namespace cg = cooperative_groups;

// ---------------------------------------------------------------------------
// Problem constants (from setup_inputs)
#define NPIX    589824     // 768*768
#define NPGRP   147456     // NPIX/4 (float4 pixel groups)
#define NEIK_G  25000      // 100000/4
#define NSDF_G  25000
#define PP      50000
#define SPTS    8192       // points per cloud

#define GRID    512        // cooperative grid: 2 blocks/CU co-resident
#define B_CHAM  256        // blocks 0..255: chamfer, 64 sources each
#define B_SUM   256        // blocks 256..511: elementwise sums (grid-stride)

// ---------------------------------------------------------------------------
// ws layout (32-bit words). Plain stores into disjoint slots; every slot is
// written exactly once per call before it is read (no init kernel needed).
// Quantities q*1024 + rel_block*4 + wave:
//   0 mask, 1 nerr, 2 den, 3 num, 4 bce, 5 eik, 6 sdf, 7 con, 8 vis
#define OFF_Q(q)  ((q)*1024)
#define OFF_DEP   9216     // 512 blocks x 4 waves = 2048
#define OFF_PC    11264    // 256 chamfer block partial sums (sqrt applied)

__device__ __forceinline__ float nan0(float x) { return isfinite(x) ? x : 0.0f; }

__device__ __forceinline__ float waveReduce(float v) {
    v += __shfl_down(v, 32); v += __shfl_down(v, 16); v += __shfl_down(v, 8);
    v += __shfl_down(v, 4);  v += __shfl_down(v, 2);  v += __shfl_down(v, 1);
    return v;
}

union F12 { float4 v[3]; float f[12]; };

// ---------------------------------------------------------------------------
__global__ __launch_bounds__(256, 2) void k_all(
    const float* __restrict__ normal_pred, const float* __restrict__ normal_gt,
    const float* __restrict__ depth_pred,  const float* __restrict__ depth_gt,
    const float* __restrict__ X,           const float* __restrict__ Y,
    const float* __restrict__ mask,        const float* __restrict__ comp_mask,
    const float* __restrict__ gradients,   const float* __restrict__ sdf,
    const float* __restrict__ nwa,         const float* __restrict__ vm,
    const float* __restrict__ wts,         float* __restrict__ ws,
    float* __restrict__ out)
{
    __shared__ float4 ybuf[1024];      // 16 KB dest tiles (chamfer)
    __shared__ float  redmin[256];     // cross-quarter min combine
    __shared__ float  sh[8];
    __shared__ float  sscale;
    __shared__ float  sbuf[4];

    cg::grid_group grid = cg::this_grid();
    int b = blockIdx.x, t = threadIdx.x;
    int lane = t & 63, w = t >> 6;

    // ======================= PHASE A =======================
    if (b < B_CHAM) {
        // ---- chamfer: block owns 64 sources, scans all 8192 dests.
        // rank r = 0.5|y|^2 - x.y; d2/2 = min r + 0.5|x|^2.
        int dir   = b >> 7;                  // 0: X->Y, 1: Y->X
        int sbase = (b & 127) * 64;
        const float* src = dir ? Y : X;
        const float* dst = dir ? X : Y;
        int s_l = t & 63, q = t >> 6;        // 4 threads per source (quarters)
        int sidx = sbase + s_l;
        float x0 = src[3*sidx], x1 = src[3*sidx+1], x2 = src[3*sidx+2];
        float hx2 = 0.5f * (x0*x0 + x1*x1 + x2*x2);
        float mn0 = 1e30f, mn1 = 1e30f, mn2 = 1e30f, mn3 = 1e30f;
        for (int stage = 0; stage < 8; ++stage) {
            // stage loads 1024 dests; thread t loads 4 consecutive (12 floats)
            int d0 = stage * 1024 + t * 4;
            const float4* p4 = (const float4*)(dst + 3 * d0);
            float4 A = p4[0], B4 = p4[1], C4 = p4[2];
            __syncthreads();                 // prior stage fully consumed
            ybuf[t*4+0] = make_float4(A.x, A.y, A.z, 0.5f*(A.x*A.x + A.y*A.y + A.z*A.z));
            ybuf[t*4+1] = make_float4(A.w, B4.x, B4.y, 0.5f*(A.w*A.w + B4.x*B4.x + B4.y*B4.y));
            ybuf[t*4+2] = make_float4(B4.z, B4.w, C4.x, 0.5f*(B4.z*B4.z + B4.w*B4.w + C4.x*C4.x));
            ybuf[t*4+3] = make_float4(C4.y, C4.z, C4.w, 0.5f*(C4.y*C4.y + C4.z*C4.z + C4.w*C4.w));
            __syncthreads();
            // quarter q consumes tile q of this stage (wave-uniform -> broadcast)
            const float4* tile = &ybuf[q * 256];
#pragma unroll 4
            for (int i = 0; i < 256; i += 4) {
                float4 ya = tile[i], yb = tile[i+1], yc = tile[i+2], yd = tile[i+3];
                float ra = fmaf(-x0, ya.x, ya.w); ra = fmaf(-x1, ya.y, ra); ra = fmaf(-x2, ya.z, ra);
                float rb = fmaf(-x0, yb.x, yb.w); rb = fmaf(-x1, yb.y, rb); rb = fmaf(-x2, yb.z, rb);
                float rc = fmaf(-x0, yc.x, yc.w); rc = fmaf(-x1, yc.y, rc); rc = fmaf(-x2, yc.z, rc);
                float rd = fmaf(-x0, yd.x, yd.w); rd = fmaf(-x1, yd.y, rd); rd = fmaf(-x2, yd.z, rd);
                mn0 = fminf(mn0, ra); mn1 = fminf(mn1, rb);
                mn2 = fminf(mn2, rc); mn3 = fminf(mn3, rd);
            }
        }
        redmin[q * 64 + s_l] = fminf(fminf(mn0, mn1), fminf(mn2, mn3));
        __syncthreads();
        if (t < 64) {                        // wave 0: combine quarters, sqrt, sum
            float m = fminf(fminf(redmin[t], redmin[64+t]),
                            fminf(redmin[128+t], redmin[192+t]));
            float d = sqrtf(fmaxf(2.0f * (m + hx2), 0.0f));
            d = waveReduce(d);
            if (t == 0) ws[OFF_PC + b] = d;  // one float per chamfer block
        }
    } else {
        // ---- elementwise sums, grid-stride over each region
        int rel = b - B_CHAM;                // 0..255
        float aMask=0, aNerr=0, aDen=0, aNum=0, aBce=0, aEik=0, aSdf=0, aCon=0, aVis=0;
        for (int g = rel * 256 + t; g < NPGRP; g += B_SUM * 256) {
            float4 m4  = ((const float4*)mask)[g];
            float4 c4  = ((const float4*)comp_mask)[g];
            float4 dg4 = ((const float4*)depth_gt)[g];
            float4 dp4 = ((const float4*)depth_pred)[g];
            F12 np, ng;
            np.v[0] = ((const float4*)normal_pred)[3*g];
            np.v[1] = ((const float4*)normal_pred)[3*g+1];
            np.v[2] = ((const float4*)normal_pred)[3*g+2];
            ng.v[0] = ((const float4*)normal_gt)[3*g];
            ng.v[1] = ((const float4*)normal_gt)[3*g+1];
            ng.v[2] = ((const float4*)normal_gt)[3*g+2];
            float mm[4] = { m4.x, m4.y, m4.z, m4.w };
            float cc[4] = { c4.x, c4.y, c4.z, c4.w };
            float gg[4] = { dg4.x, dg4.y, dg4.z, dg4.w };
            float pp[4] = { dp4.x, dp4.y, dp4.z, dp4.w };
#pragma unroll
            for (int k = 0; k < 4; ++k) {
                float m = mm[k] > 0.5f ? 1.0f : 0.0f;
                aMask += m;
                float e0 = nan0(np.f[3*k])   - nan0(ng.f[3*k]);
                float e1 = nan0(np.f[3*k+1]) - nan0(ng.f[3*k+1]);
                float e2 = nan0(np.f[3*k+2]) - nan0(ng.f[3*k+2]);
                aNerr += m * (e0*e0 + e1*e1 + e2*e2);
                float vg = (m == 1.0f) ? nan0(gg[k]) : 0.0f;
                float vp = (m == 1.0f) ? nan0(pp[k]) : 0.0f;
                aDen += vg * vg;
                aNum += vg * vp;
                float c = cc[k];
                c = fminf(fmaxf(c, 0.0f), 1.0f);   // clip; +inf->1, -inf->0
                if (isnan(c)) c = 0.5f;            // nan->0.5
                c = fminf(fmaxf(c, 1e-5f), 1.0f - 1e-5f);
                aBce -= m * __logf(c) + (1.0f - m) * __logf(1.0f - c);
            }
        }
        {   // eikonal: groups of 4 points (exactly 25000 groups)
            int i = rel * 256 + t;
            if (i < NEIK_G) {
                F12 gr;
                gr.v[0] = ((const float4*)gradients)[3*i];
                gr.v[1] = ((const float4*)gradients)[3*i+1];
                gr.v[2] = ((const float4*)gradients)[3*i+2];
#pragma unroll
                for (int k = 0; k < 4; ++k) {
                    float g0 = gr.f[3*k], g1 = gr.f[3*k+1], g2 = gr.f[3*k+2];
                    float n = sqrtf(g0*g0 + g1*g1 + g2*g2) - 1.0f;
                    aEik += n * n;
                }
            }
        }
        {   // sdf: groups of 4
            int i = rel * 256 + t;
            if (i < NSDF_G) {
                float4 s4 = ((const float4*)sdf)[i];
                aSdf = fabsf(s4.x) + fabsf(s4.y) + fabsf(s4.z) + fabsf(s4.w);
            }
        }
        {   // consistency: one point, 3 cam pairs
            int p = rel * 256 + t;
            if (p < PP) {
                F12 a;
                a.v[0] = ((const float4*)nwa)[3*p];
                a.v[1] = ((const float4*)nwa)[3*p+1];
                a.v[2] = ((const float4*)nwa)[3*p+2];
                float4 v4 = ((const float4*)vm)[p];
                float vv[4] = { v4.x, v4.y, v4.z, v4.w };
                float wt = wts[p];
#pragma unroll
                for (int pr = 0; pr < 3; ++pr) {
                    float d0 = a.f[3*pr]   - a.f[3*pr+3];
                    float d1 = a.f[3*pr+1] - a.f[3*pr+4];
                    float d2 = a.f[3*pr+2] - a.f[3*pr+5];
                    float mse = d0*d0 + d1*d1 + d2*d2;
                    float vis = vv[pr] * vv[pr+1];
                    aVis += vis;
                    aCon += mse * vis * wt;
                }
            }
        }
        aMask = waveReduce(aMask); aNerr = waveReduce(aNerr);
        aDen  = waveReduce(aDen);  aNum  = waveReduce(aNum);
        aBce  = waveReduce(aBce);  aEik  = waveReduce(aEik);
        aSdf  = waveReduce(aSdf);  aCon  = waveReduce(aCon);
        aVis  = waveReduce(aVis);
        if (lane == 0) {
            int idx = rel * 4 + w;
            ws[OFF_Q(0) + idx] = aMask; ws[OFF_Q(1) + idx] = aNerr;
            ws[OFF_Q(2) + idx] = aDen;  ws[OFF_Q(3) + idx] = aNum;
            ws[OFF_Q(4) + idx] = aBce;  ws[OFF_Q(5) + idx] = aEik;
            ws[OFF_Q(6) + idx] = aSdf;  ws[OFF_Q(7) + idx] = aCon;
            ws[OFF_Q(8) + idx] = aVis;
        }
    }
    __threadfence();
    grid.sync();

    // ======================= PHASE B: depth pass 2 =======================
    {   // every block computes scale from den/num partials (L2 reads)
        float pd = 0, pn = 0;
        for (int i = t; i < 1024; i += 256) {
            pd += ws[OFF_Q(2) + i];
            pn += ws[OFF_Q(3) + i];
        }
        pd = waveReduce(pd); pn = waveReduce(pn);
        __syncthreads();
        if (lane == 0) { sh[w] = pd; sh[4 + w] = pn; }
        __syncthreads();
        if (t == 0) {
            float den = sh[0] + sh[1] + sh[2] + sh[3];
            float num = sh[4] + sh[5] + sh[6] + sh[7];
            float sc = num / den;
            if (!isfinite(sc)) sc = 1.0f;    // nan_to_num(nan=1, +-inf=1)
            sscale = sc;
        }
        __syncthreads();
        float scale = sscale;
        float acc = 0;
        for (int g = b * 256 + t; g < NPGRP; g += GRID * 256) {
            float4 m4  = ((const float4*)mask)[g];
            float4 dg4 = ((const float4*)depth_gt)[g];
            float4 dp4 = ((const float4*)depth_pred)[g];
            float mm[4] = { m4.x, m4.y, m4.z, m4.w };
            float gg[4] = { dg4.x, dg4.y, dg4.z, dg4.w };
            float pq[4] = { dp4.x, dp4.y, dp4.z, dp4.w };
#pragma unroll
            for (int k = 0; k < 4; ++k) {
                float m  = mm[k] > 0.5f ? 1.0f : 0.0f;
                float vg = (m == 1.0f) ? nan0(gg[k]) : 0.0f;
                float vp = (m == 1.0f) ? nan0(pq[k]) : 0.0f;
                acc += fabsf(vg * scale - vp);
            }
        }
        acc = waveReduce(acc);
        if (lane == 0) ws[OFF_DEP + b * 4 + w] = acc;
    }
    __threadfence();
    grid.sync();

    // ======================= PHASE C: block 0 assembles ==================
    if (b != 0) return;
    {
        float sums[10];
        const int offs[10] = { OFF_Q(0), OFF_Q(1), OFF_Q(2), OFF_Q(4), OFF_Q(5),
                               OFF_Q(6), OFF_Q(7), OFF_Q(8), OFF_DEP, OFF_PC };
        const int lens[10] = { 1024, 1024, 1024, 1024, 1024, 1024, 1024, 1024, 2048, 256 };
#pragma unroll
        for (int a = 0; a < 10; ++a) {
            float s = 0;
            for (int i = t; i < lens[a]; i += 256) s += ws[offs[a] + i];
            s = waveReduce(s);
            __syncthreads();
            if (lane == 0) sbuf[w] = s;
            __syncthreads();
            sums[a] = sbuf[0] + sbuf[1] + sbuf[2] + sbuf[3];
        }
        if (t == 0) {
            float mask_sum = sums[0] + 1e-5f;
            float normal_loss = sums[1] / mask_sum;
            float depth_loss = sums[8] / (mask_sum + 1e-8f);
            if (sums[2] < 1e-10f) depth_loss = 0.0f;
            depth_loss = nan0(depth_loss);
            float pc_loss  = sums[9] / (float)SPTS;  // both dirs share /8192
            float bce_l    = sums[3] / (float)NPIX;
            float eik_l    = sums[4] / 100000.0f;
            float sdf_l    = sums[5] / 100000.0f;
            float con_l    = sums[7] > 0.0f ? sums[6] / sums[7] : 0.0f;
            out[0] = normal_loss + depth_loss + pc_loss + bce_l + eik_l + sdf_l + con_l;
        }
    }
}

// ---------------------------------------------------------------------------
extern "C" void kernel_launch(void* const* d_in, const int* in_sizes, int n_in,
                              void* d_out, int out_size, void* d_ws, size_t ws_size,
                              hipStream_t stream) {
    const float* normal_pred = (const float*)d_in[0];
    const float* normal_gt   = (const float*)d_in[1];
    const float* depth_pred  = (const float*)d_in[2];
    const float* depth_gt    = (const float*)d_in[3];
    const float* X           = (const float*)d_in[4];
    const float* Y           = (const float*)d_in[5];
    const float* mask        = (const float*)d_in[6];
    const float* comp_mask   = (const float*)d_in[7];
    const float* gradients   = (const float*)d_in[8];
    const float* sdf         = (const float*)d_in[9];
    const float* nwa         = (const float*)d_in[10];
    const float* vm          = (const float*)d_in[11];
    const float* wts         = (const float*)d_in[12];
    float* ws  = (float*)d_ws;
    float* out = (float*)d_out;

    void* args[] = { &normal_pred, &normal_gt, &depth_pred, &depth_gt,
                     &X, &Y, &mask, &comp_mask, &gradients, &sdf,
                     &nwa, &vm, &wts, &ws, &out };
    hipLaunchCooperativeKernel((void*)k_all, dim3(GRID), dim3(256),
                               args, 0, stream);
}

// Round 6
// 134.647 us; speedup vs baseline: 2.5996x; 2.5996x over previous
//
#include <hip/hip_runtime.h>
#include <hip/hip_bf16.h>
#include <math.h>

// ---------------------------------------------------------------------------
// Problem constants (from setup_inputs)
#define NPIX   589824      // 768*768
#define NEIK   100000
#define NSDF   100000
#define PP     50000
#define SPTS   8192        // points per cloud

// k_main regions (256 thr / block)
#define B_CHAM 512         // 2 dirs x 4 src-chunks(2048) x 64 dst-chunks(128)
#define B_PIX  576         // 576*256 threads, 4 pixels each = NPIX
#define B_EIK  98          // 4 points/thread, guard at 25000 groups
#define B_SDF  98
#define B_CON  196         // 1 point/thread, guard 50000
#define B_MAIN (B_CHAM + B_PIX + B_EIK + B_SDF + B_CON)   // 1480
// k_mid regions
#define B_DEP  576         // depth pass 2: 4 pixels/thread
#define B_PC   64          // chamfer partial-min reduce: 64*256 = 16384 sources
#define B_MID  (B_DEP + B_PC)

// ---------------------------------------------------------------------------
// ws layout (32-bit words). ALL outputs are plain stores into disjoint slots:
// no atomics anywhere, no initialization required (every read slot is written
// exactly once by an earlier kernel in the same call).
#define OFF_MASK  0        // 2304 wave partials (576 blocks x 4 waves)
#define OFF_NERR  2304
#define OFF_DEN   4608
#define OFF_NUM   6912
#define OFF_BCE   9216
#define OFF_EIK   11520    // 392
#define OFF_SDF   11912    // 392
#define OFF_CON   12304    // 784
#define OFF_VIS   13088    // 784
#define OFF_DEP   13872    // 2304
#define OFF_PC    16176    // 256
#define OFF_CHAM  16640    // 64 dst-chunk partials x 16384 sources = 1048576 words

__device__ __forceinline__ float nan0(float x) { return isfinite(x) ? x : 0.0f; }

__device__ __forceinline__ float waveReduce(float v) {
    v += __shfl_down(v, 32); v += __shfl_down(v, 16); v += __shfl_down(v, 8);
    v += __shfl_down(v, 4);  v += __shfl_down(v, 2);  v += __shfl_down(v, 1);
    return v;
}

// valid on thread 0 only; block must be 256 threads (4 waves)
__device__ __forceinline__ float blockReduce(float v, float* sbuf) {
    v = waveReduce(v);
    int lane = threadIdx.x & 63, w = threadIdx.x >> 6;
    __syncthreads();                  // protect sbuf across back-to-back calls
    if (lane == 0) sbuf[w] = v;
    __syncthreads();
    float r = 0.0f;
    if (threadIdx.x == 0) r = sbuf[0] + sbuf[1] + sbuf[2] + sbuf[3];
    return r;
}

__device__ __forceinline__ float blockSumArr(const float* a, int n, float* sbuf) {
    float s = 0;
    for (int i = threadIdx.x; i < n; i += 256) s += a[i];
    return blockReduce(s, sbuf);      // thread 0 only
}

union F12 { float4 v[3]; float f[12]; };

// ---------------------------------------------------------------------------
__global__ __launch_bounds__(256) void k_main(
    const float* __restrict__ normal_pred, const float* __restrict__ normal_gt,
    const float* __restrict__ depth_pred,  const float* __restrict__ depth_gt,
    const float* __restrict__ X,           const float* __restrict__ Y,
    const float* __restrict__ mask,        const float* __restrict__ comp_mask,
    const float* __restrict__ gradients,   const float* __restrict__ sdf,
    const float* __restrict__ nwa,         const float* __restrict__ vm,
    const float* __restrict__ wts,         float* __restrict__ ws)
{
    int b = blockIdx.x, t = threadIdx.x;
    int lane = t & 63, w = t >> 6;
    if (b < B_CHAM) {
        // ---- chamfer partials: rank r = 0.5|y|^2 - x.y (3 FMA + 1 min/pair);
        // 8 sources/thread -> one ds_read_b128 feeds 32 VALU ops.
        // partial-min + 0.5|x|^2 = min d2/2 over this 128-dst chunk, plain store.
        int dir = b >> 8;            // 0: X->Y, 1: Y->X
        int r   = b & 255;
        int sc  = r >> 6;            // src chunk 0..3 (2048 sources)
        int dc  = r & 63;            // dst chunk 0..63 (128 dests)
        const float* src = dir ? Y : X;
        const float* dst = dir ? X : Y;
        __shared__ float4 ybuf[128];
        if (t < 128) {
            int d = dc * 128 + t;
            float y0 = dst[3*d], y1 = dst[3*d+1], y2 = dst[3*d+2];
            ybuf[t] = make_float4(y0, y1, y2, 0.5f * (y0*y0 + y1*y1 + y2*y2));
        }
        float nx0[8], nx1[8], nx2[8], hx2[8], mn[8];
#pragma unroll
        for (int j = 0; j < 8; ++j) {
            int s = sc * 2048 + t + j * 256;
            float x0 = src[3*s], x1 = src[3*s+1], x2 = src[3*s+2];
            nx0[j] = -x0; nx1[j] = -x1; nx2[j] = -x2;
            hx2[j] = 0.5f * (x0*x0 + x1*x1 + x2*x2);
            mn[j]  = 1e30f;
        }
        __syncthreads();
#pragma unroll 2
        for (int dd = 0; dd < 128; ++dd) {
            float4 y = ybuf[dd];     // wave-uniform address -> LDS broadcast
#pragma unroll
            for (int j = 0; j < 8; ++j) {
                float rr = fmaf(nx0[j], y.x, y.w);
                rr = fmaf(nx1[j], y.y, rr);
                rr = fmaf(nx2[j], y.z, rr);
                mn[j] = fminf(mn[j], rr);
            }
        }
        int base = OFF_CHAM + dc * 16384 + dir * 8192 + sc * 2048 + t;
#pragma unroll
        for (int j = 0; j < 8; ++j)
            ws[base + j * 256] = mn[j] + hx2[j];   // coalesced plain store
    } else if (b < B_CHAM + B_PIX) {
        int pb = b - B_CHAM;
        int g = pb * 256 + t;                      // pixel group, 4 pixels
        float4 m4  = ((const float4*)mask)[g];
        float4 c4  = ((const float4*)comp_mask)[g];
        float4 dg4 = ((const float4*)depth_gt)[g];
        float4 dp4 = ((const float4*)depth_pred)[g];
        F12 np, ng;
        np.v[0] = ((const float4*)normal_pred)[3*g];
        np.v[1] = ((const float4*)normal_pred)[3*g+1];
        np.v[2] = ((const float4*)normal_pred)[3*g+2];
        ng.v[0] = ((const float4*)normal_gt)[3*g];
        ng.v[1] = ((const float4*)normal_gt)[3*g+1];
        ng.v[2] = ((const float4*)normal_gt)[3*g+2];
        float mm[4] = { m4.x, m4.y, m4.z, m4.w };
        float cc[4] = { c4.x, c4.y, c4.z, c4.w };
        float gg[4] = { dg4.x, dg4.y, dg4.z, dg4.w };
        float pp[4] = { dp4.x, dp4.y, dp4.z, dp4.w };
        float s_mask = 0, s_nerr = 0, s_den = 0, s_num = 0, s_bce = 0;
#pragma unroll
        for (int k = 0; k < 4; ++k) {
            float m = mm[k] > 0.5f ? 1.0f : 0.0f;
            s_mask += m;
            float e0 = nan0(np.f[3*k])   - nan0(ng.f[3*k]);
            float e1 = nan0(np.f[3*k+1]) - nan0(ng.f[3*k+1]);
            float e2 = nan0(np.f[3*k+2]) - nan0(ng.f[3*k+2]);
            s_nerr += m * (e0*e0 + e1*e1 + e2*e2);
            float vg = (m == 1.0f) ? nan0(gg[k]) : 0.0f;
            float vp = (m == 1.0f) ? nan0(pp[k]) : 0.0f;
            s_den += vg * vg;
            s_num += vg * vp;
            float c = cc[k];
            c = fminf(fmaxf(c, 0.0f), 1.0f);       // clip; +inf->1, -inf->0
            if (isnan(c)) c = 0.5f;                // nan->0.5
            c = fminf(fmaxf(c, 1e-5f), 1.0f - 1e-5f);
            s_bce -= m * __logf(c) + (1.0f - m) * __logf(1.0f - c);
        }
        s_mask = waveReduce(s_mask); s_nerr = waveReduce(s_nerr);
        s_den  = waveReduce(s_den);  s_num  = waveReduce(s_num);
        s_bce  = waveReduce(s_bce);
        if (lane == 0) {
            int idx = pb * 4 + w;                  // per-wave partial slot
            ws[OFF_MASK + idx] = s_mask;
            ws[OFF_NERR + idx] = s_nerr;
            ws[OFF_DEN  + idx] = s_den;
            ws[OFF_NUM  + idx] = s_num;
            ws[OFF_BCE  + idx] = s_bce;
        }
    } else if (b < B_CHAM + B_PIX + B_EIK) {
        int eb = b - (B_CHAM + B_PIX);
        int i = eb * 256 + t;                      // group of 4 points
        float acc = 0;
        if (i < NEIK / 4) {
            F12 gr;
            gr.v[0] = ((const float4*)gradients)[3*i];
            gr.v[1] = ((const float4*)gradients)[3*i+1];
            gr.v[2] = ((const float4*)gradients)[3*i+2];
#pragma unroll
            for (int k = 0; k < 4; ++k) {
                float g0 = gr.f[3*k], g1 = gr.f[3*k+1], g2 = gr.f[3*k+2];
                float n = sqrtf(g0*g0 + g1*g1 + g2*g2) - 1.0f;
                acc += n * n;
            }
        }
        acc = waveReduce(acc);
        if (lane == 0) ws[OFF_EIK + eb * 4 + w] = acc;
    } else if (b < B_CHAM + B_PIX + B_EIK + B_SDF) {
        int sb = b - (B_CHAM + B_PIX + B_EIK);
        int i = sb * 256 + t;                      // group of 4
        float acc = 0;
        if (i < NSDF / 4) {
            float4 s4 = ((const float4*)sdf)[i];
            acc = fabsf(s4.x) + fabsf(s4.y) + fabsf(s4.z) + fabsf(s4.w);
        }
        acc = waveReduce(acc);
        if (lane == 0) ws[OFF_SDF + sb * 4 + w] = acc;
    } else {
        int cb = b - (B_CHAM + B_PIX + B_EIK + B_SDF);
        int p = cb * 256 + t;                      // one point, 3 cam pairs
        float s_con = 0, s_vis = 0;
        if (p < PP) {
            F12 a;
            a.v[0] = ((const float4*)nwa)[3*p];
            a.v[1] = ((const float4*)nwa)[3*p+1];
            a.v[2] = ((const float4*)nwa)[3*p+2];
            float4 v4 = ((const float4*)vm)[p];
            float vv[4] = { v4.x, v4.y, v4.z, v4.w };
            float wt = wts[p];
#pragma unroll
            for (int pr = 0; pr < 3; ++pr) {
                float d0 = a.f[3*pr]   - a.f[3*pr+3];
                float d1 = a.f[3*pr+1] - a.f[3*pr+4];
                float d2 = a.f[3*pr+2] - a.f[3*pr+5];
                float mse = d0*d0 + d1*d1 + d2*d2;
                float vis = vv[pr] * vv[pr+1];
                s_vis += vis;
                s_con += mse * vis * wt;
            }
        }
        s_con = waveReduce(s_con); s_vis = waveReduce(s_vis);
        if (lane == 0) {
            ws[OFF_CON + cb * 4 + w] = s_con;
            ws[OFF_VIS + cb * 4 + w] = s_vis;
        }
    }
}

// ---------------------------------------------------------------------------
// depth pass 2 (scale recomputed per block from den/num wave partials) +
// chamfer partial-min reduction.
__global__ __launch_bounds__(256) void k_mid(
    const float* __restrict__ depth_pred, const float* __restrict__ depth_gt,
    const float* __restrict__ mask, float* __restrict__ ws)
{
    int b = blockIdx.x, t = threadIdx.x;
    int lane = t & 63, w = t >> 6;
    if (b < B_DEP) {
        __shared__ float sh[8];
        __shared__ float sscale;
        float pd = 0, pn = 0;
        for (int i = t; i < 2304; i += 256) {
            pd += ws[OFF_DEN + i];
            pn += ws[OFF_NUM + i];
        }
        pd = waveReduce(pd); pn = waveReduce(pn);
        if (lane == 0) { sh[w] = pd; sh[4 + w] = pn; }
        __syncthreads();
        if (t == 0) {
            float den = sh[0] + sh[1] + sh[2] + sh[3];
            float num = sh[4] + sh[5] + sh[6] + sh[7];
            float sc = num / den;
            if (!isfinite(sc)) sc = 1.0f;          // nan_to_num(nan=1, +-inf=1)
            sscale = sc;
        }
        __syncthreads();
        float scale = sscale;
        int g = b * 256 + t;                       // 4 pixels per thread
        float4 m4  = ((const float4*)mask)[g];
        float4 dg4 = ((const float4*)depth_gt)[g];
        float4 dp4 = ((const float4*)depth_pred)[g];
        float mm[4] = { m4.x, m4.y, m4.z, m4.w };
        float gg[4] = { dg4.x, dg4.y, dg4.z, dg4.w };
        float pp[4] = { dp4.x, dp4.y, dp4.z, dp4.w };
        float acc = 0;
#pragma unroll
        for (int k = 0; k < 4; ++k) {
            float m  = mm[k] > 0.5f ? 1.0f : 0.0f;
            float vg = (m == 1.0f) ? nan0(gg[k]) : 0.0f;
            float vp = (m == 1.0f) ? nan0(pp[k]) : 0.0f;
            acc += fabsf(vg * scale - vp);
        }
        acc = waveReduce(acc);
        if (lane == 0) ws[OFF_DEP + b * 4 + w] = acc;
    } else {
        int rb = b - B_DEP;
        int g = rb * 256 + t;                      // source id, 0..16383
        float mn = 1e30f;
#pragma unroll 8
        for (int dc = 0; dc < 64; ++dc)
            mn = fminf(mn, ws[OFF_CHAM + dc * 16384 + g]);  // coalesced
        float v = sqrtf(fmaxf(2.0f * mn, 0.0f));   // sqrt(d2_min)
        v = waveReduce(v);
        if (lane == 0) ws[OFF_PC + rb * 4 + w] = v;
    }
}

// ---------------------------------------------------------------------------
// single block: sum all wave partials, assemble the loss.
__global__ __launch_bounds__(256) void k_finalize(
    const float* __restrict__ ws, float* __restrict__ out)
{
    __shared__ float sbuf[4];
    int t = threadIdx.x;
    float mask_s = blockSumArr(ws + OFF_MASK, 2304, sbuf);
    float nerr   = blockSumArr(ws + OFF_NERR, 2304, sbuf);
    float den    = blockSumArr(ws + OFF_DEN,  2304, sbuf);
    float bce    = blockSumArr(ws + OFF_BCE,  2304, sbuf);
    float eik    = blockSumArr(ws + OFF_EIK,  392,  sbuf);
    float sdfs   = blockSumArr(ws + OFF_SDF,  392,  sbuf);
    float con    = blockSumArr(ws + OFF_CON,  784,  sbuf);
    float vis    = blockSumArr(ws + OFF_VIS,  784,  sbuf);
    float dep    = blockSumArr(ws + OFF_DEP,  2304, sbuf);
    float pc     = blockSumArr(ws + OFF_PC,   256,  sbuf);
    if (t == 0) {
        float mask_sum = mask_s + 1e-5f;
        float normal_loss = nerr / mask_sum;
        float depth_loss = dep / (mask_sum + 1e-8f);
        if (den < 1e-10f) depth_loss = 0.0f;
        depth_loss = nan0(depth_loss);
        float pc_loss  = pc / (float)SPTS;         // both dirs share /8192
        float bce_l    = bce / (float)NPIX;
        float eik_l    = eik / (float)NEIK;
        float sdf_l    = sdfs / (float)NSDF;
        float con_l    = vis > 0.0f ? con / vis : 0.0f;
        out[0] = normal_loss + depth_loss + pc_loss + bce_l + eik_l + sdf_l + con_l;
    }
}

// ---------------------------------------------------------------------------
extern "C" void kernel_launch(void* const* d_in, const int* in_sizes, int n_in,
                              void* d_out, int out_size, void* d_ws, size_t ws_size,
                              hipStream_t stream) {
    const float* normal_pred = (const float*)d_in[0];
    const float* normal_gt   = (const float*)d_in[1];
    const float* depth_pred  = (const float*)d_in[2];
    const float* depth_gt    = (const float*)d_in[3];
    const float* X           = (const float*)d_in[4];
    const float* Y           = (const float*)d_in[5];
    const float* mask        = (const float*)d_in[6];
    const float* comp_mask   = (const float*)d_in[7];
    const float* gradients   = (const float*)d_in[8];
    const float* sdf         = (const float*)d_in[9];
    const float* nwa         = (const float*)d_in[10];
    const float* vm          = (const float*)d_in[11];
    const float* wts         = (const float*)d_in[12];
    float* ws  = (float*)d_ws;
    float* out = (float*)d_out;

    k_main<<<dim3(B_MAIN), dim3(256), 0, stream>>>(
        normal_pred, normal_gt, depth_pred, depth_gt, X, Y, mask, comp_mask,
        gradients, sdf, nwa, vm, wts, ws);
    k_mid<<<dim3(B_MID), dim3(256), 0, stream>>>(depth_pred, depth_gt, mask, ws);
    k_finalize<<<dim3(1), dim3(256), 0, stream>>>(ws, out);
}